// Round 1
// baseline (42.600 us; speedup 1.0000x reference)
//
#include <hip/hip_runtime.h>
#include <math.h>

#define F_LEN 21
#define D_LEN 41
#define S_LEN 61          // F_LEN + D_LEN - 1
#define ROWS_PB 256       // rows per block == blockDim.x
#define CH 16             // staging chunk width (columns)
#define PAD 17            // LDS row pitch (floats) to avoid bank conflicts

// One thread per (b,l) row. Inputs staged via LDS for coalesced global access,
// then consumed from fully-unrolled register arrays (static indexing only).
__global__ __launch_bounds__(ROWS_PB, 2) void bp_kernel(
    const float* __restrict__ pf_g, const float* __restrict__ pb_g,
    const float* __restrict__ slop_g, const float* __restrict__ amp_g,
    float* __restrict__ out_dist, float* __restrict__ out_mean,
    float* __restrict__ out_ivar)
{
    __shared__ float lds_a[ROWS_PB * PAD];
    __shared__ float lds_b[ROWS_PB * PAD];

    const int tid  = threadIdx.x;
    const int row0 = blockIdx.x * ROWS_PB;
    const int r    = row0 + tid;

    float pbv[S_LEN];   // pb values
    float dfv[S_LEN];   // pf - pb

    // ---- staged, coalesced load of pf/pb rows into registers -------------
    #pragma unroll
    for (int c = 0; c < 4; ++c) {
        const int s0 = c * CH;
        #pragma unroll
        for (int it = 0; it < CH; ++it) {
            int idx = it * ROWS_PB + tid;      // 0 .. 4095 over the block
            int lr  = idx >> 4;                // local row   (CH == 16)
            int lc  = idx & 15;                // local col
            int s   = s0 + lc;
            if (s < S_LEN) {
                size_t g = (size_t)(row0 + lr) * S_LEN + s;
                lds_a[lr * PAD + lc] = pf_g[g];
                lds_b[lr * PAD + lc] = pb_g[g];
            }
        }
        __syncthreads();
        #pragma unroll
        for (int k = 0; k < CH; ++k) {
            int s = s0 + k;                    // compile-time constant
            if (s < S_LEN) {
                float f = lds_a[tid * PAD + k];
                float b = lds_b[tid * PAD + k];
                pbv[s] = b;
                dfv[s] = f - b;
            }
        }
        __syncthreads();
    }

    // ---- per-row scalars --------------------------------------------------
    const float a  = amp_g[r];
    const float sl = slop_g[r];

    // lf[j] = 0.5 - a * tanh((j-10)/(2*slop)); tanh via E = exp(1/slop) powers
    float lf[F_LEN];
    lf[10] = 0.5f;
    {
        const float E = __expf(1.0f / sl);     // e^{1/slop}; slop>=0.5 -> finite
        float Ek = 1.0f;
        #pragma unroll
        for (int k = 1; k <= 10; ++k) {
            Ek *= E;                           // e^{k/slop}
            float t = (Ek - 1.0f) / (Ek + 1.0f);   // tanh(k/(2*slop))
            float d = a * t;
            lf[10 + k] = 0.5f - d;
            lf[10 - k] = 0.5f + d;
        }
    }

    // ---- main sliding-window log-sum loop (fully unrolled, static idx) ---
    float dist[D_LEN];
    float sum = 0.0f, sum1 = 0.0f, sum2 = 0.0f;
    #pragma unroll
    for (int d = 0; d < D_LEN; ++d) {
        float acc = 0.0f;
        #pragma unroll
        for (int j = 0; j < F_LEN; ++j) {
            float term = fmaf(lf[j], dfv[d + j], pbv[d + j]); // pb + lf*(pf-pb)
            acc += __log2f(term);              // v_log_f32
        }
        float e = exp2f(acc);
        dist[d] = e;
        sum  += e;
        sum1 += (float)d * e;
        sum2 += (float)(d * d) * e;
    }

    const float inv      = 1.0f / fmaxf(sum, 1e-12f);
    const float mean_tmp = sum1 * inv;
    const float m2       = sum2 * inv;
    const float var_tmp  = fmaf(-mean_tmp, mean_tmp, m2);

    // min variance floor: 1/(2*atanh(2a)^2) vs slop; var >= slop >= 0.5
    const float two_a = 2.0f * a;
    const float at    = 0.5f * logf((1.0f + two_a) / (1.0f - two_a));
    const float min_v = fmaxf(0.5f / (at * at), sl);
    const float var   = fmaxf(var_tmp, min_v);

    out_mean[r] = mean_tmp - (float)((D_LEN - 1) / 2);
    out_ivar[r] = 1.0f / var;

    // ---- staged, coalesced store of normalized dist ----------------------
    #pragma unroll
    for (int c = 0; c < 3; ++c) {
        #pragma unroll
        for (int k = 0; k < CH; ++k) {
            int d = c * CH + k;                // compile-time constant
            if (d < D_LEN) lds_a[tid * PAD + k] = dist[d] * inv;
        }
        __syncthreads();
        #pragma unroll
        for (int it = 0; it < CH; ++it) {
            int idx = it * ROWS_PB + tid;
            int lr  = idx >> 4;
            int lc  = idx & 15;
            int d   = c * CH + lc;
            if (d < D_LEN) {
                out_dist[(size_t)(row0 + lr) * D_LEN + d] = lds_a[lr * PAD + lc];
            }
        }
        __syncthreads();
    }
}

extern "C" void kernel_launch(void* const* d_in, const int* in_sizes, int n_in,
                              void* d_out, int out_size, void* d_ws, size_t ws_size,
                              hipStream_t stream) {
    // inputs: [0] lines_feature (unused), [1] pf, [2] pb, [3] slop, [4] amp
    const float* pf   = (const float*)d_in[1];
    const float* pb   = (const float*)d_in[2];
    const float* slop = (const float*)d_in[3];
    const float* amp  = (const float*)d_in[4];

    const int rows = in_sizes[3];              // B * L = 131072

    float* out_dist = (float*)d_out;
    float* out_mean = out_dist + (size_t)rows * D_LEN;
    float* out_ivar = out_mean + rows;

    const int blocks = rows / ROWS_PB;         // 131072 / 256 = 512
    bp_kernel<<<blocks, ROWS_PB, 0, stream>>>(pf, pb, slop, amp,
                                              out_dist, out_mean, out_ivar);
}